// Round 13
// baseline (162.841 us; speedup 1.0000x reference)
//
#include <hip/hip_runtime.h>
#include <math.h>

// DynamicElementAggregator: B=2, N=1024, M=1024, D=768, F=384, H=72
#define B_ 2
#define N_ 1024
#define M_ 1024
#define D_ 768
#define F_ 384
#define H_ 72
#define ROWS 8      // rows per block
#define PFH 3       // heads prefetched into LDS during the MLP phase
#define RPF 6       // heads prefetched into REGISTERS during the MLP phase

typedef float f32x4 __attribute__((ext_vector_type(4)));

// ---- Fully fused, wave-specialized (R10 base + register head-prefetch):
//   phase 0: all 512 stage x rows to LDS
//   phase 1: ALL threads first issue NT loads for heads 3..8 of their own
//            combine slice into registers (latency hidden by layer-1);
//            then t<384 run layer-1 (1 col each), t>=384 stream heads 0..2
//            of the score slab into LDS (96 KB).
//   phase 2: layer-2 -> rwv;  phase 3: combine (regs + LDS + global stream).
// 256 blocks x 512 threads, 8 rows/block, 1 block/CU (134.75 KB LDS).
__global__ __launch_bounds__(512) void fused_kernel(
    const float* __restrict__ x, const float* __restrict__ scores,
    const float* __restrict__ W1, const float* __restrict__ b1,
    const float* __restrict__ W2, const float* __restrict__ b2,
    const float* __restrict__ bias, float* __restrict__ out)
{
    const int t = threadIdx.x;            // 0..511
    const int blk = blockIdx.x;           // 0..255
    const int b = blk >> 7;
    const int n0 = (blk & 127) * ROWS;
    const int row0 = (b << 10) + n0;      // global flattened row

    __shared__ float xs[ROWS][D_];            // 24 KB
    __shared__ float hs[ROWS][F_ + 8];        // 12.25 KB (pitch 392)
    __shared__ float rwv[ROWS][80];           // 2.5 KB
    __shared__ float pf[PFH][ROWS][M_];       // 96 KB

    const f32x4* __restrict__ sp = reinterpret_cast<const f32x4*>(scores);
    const int hstr = N_ * (M_ / 4);           // float4 per head panel
    const int sbase = ((b * H_) * N_ + n0) * (M_ / 4);  // (b, h=0, n0, 0)

    // combine-slice coordinates (needed early for the register prefetch)
    const int col = t & 255;
    const int r0v = (t >> 8) * 4;             // 0 or 4
    const int base = sbase + r0v * (M_ / 4) + col;

    // ---- phase 0: stage x rows into LDS (1536 float4 / 512 threads) ----
    {
        const f32x4* xg = reinterpret_cast<const f32x4*>(x + row0 * D_);
        f32x4* xl = reinterpret_cast<f32x4*>(&xs[0][0]);
#pragma unroll
        for (int i = 0; i < 3; ++i)
            xl[t + i * 512] = xg[t + i * 512];
    }
    __syncthreads();   // b0: xs ready (reg-prefetch issued AFTER this drain)

    // ---- phase 1a: register prefetch of heads PFH..PFH+RPF-1 (all threads)
    f32x4 pv[RPF][4];
#pragma unroll
    for (int u = 0; u < RPF; ++u) {
        const int ib = base + (PFH + u) * hstr;
        pv[u][0] = __builtin_nontemporal_load(sp + ib);
        pv[u][1] = __builtin_nontemporal_load(sp + ib + 256);
        pv[u][2] = __builtin_nontemporal_load(sp + ib + 512);
        pv[u][3] = __builtin_nontemporal_load(sp + ib + 768);
    }

    // ---- phase 1b: layer-1 (t<384) || LDS score prefetch (t>=384) ----
    if (t < 384) {
        const int f = t;
        float acc[ROWS];
#pragma unroll
        for (int r = 0; r < ROWS; ++r) acc[r] = 0.0f;

#pragma unroll 4
        for (int d = 0; d < D_; d += 4) {
            const float w0 = W1[(d + 0) * F_ + f];
            const float w1v = W1[(d + 1) * F_ + f];
            const float w2v = W1[(d + 2) * F_ + f];
            const float w3v = W1[(d + 3) * F_ + f];
#pragma unroll
            for (int r = 0; r < ROWS; ++r) {
                const float4 xv = *reinterpret_cast<const float4*>(&xs[r][d]);
                acc[r] = fmaf(xv.x, w0, acc[r]);
                acc[r] = fmaf(xv.y, w1v, acc[r]);
                acc[r] = fmaf(xv.z, w2v, acc[r]);
                acc[r] = fmaf(xv.w, w3v, acc[r]);
            }
        }
        const float bb = b1[f];
#pragma unroll
        for (int r = 0; r < ROWS; ++r) {
            const float v = acc[r] + bb;
            hs[r][f] = 0.5f * v * (1.0f + erff(v * 0.70710678118654752f));
        }
    } else {
        // 128 threads stream PFH*ROWS*256 = 6144 float4 (96 KB) into pf.
        const int j = t - 384;                // 0..127
        f32x4* pfl = reinterpret_cast<f32x4*>(&pf[0][0][0]);
#pragma unroll 1
        for (int base_i = 0; base_i < PFH * ROWS * 256; base_i += 128 * 12) {
            f32x4 tmp[12];                    // 12 NT loads in flight
#pragma unroll
            for (int u = 0; u < 12; ++u) {
                const int i = base_i + u * 128 + j;
                const int h = i >> 11;        // / (ROWS*256)
                const int rem = i & 2047;     // r*256 + c
                tmp[u] = __builtin_nontemporal_load(sp + sbase + h * hstr + rem);
            }
#pragma unroll
            for (int u = 0; u < 12; ++u)
                pfl[base_i + u * 128 + j] = tmp[u];
        }
    }
    __syncthreads();   // b1: hs + pf ready (pv loads long since returned)

    // ---- phase 2: layer-2 (all 512 threads, 576 outputs) ----
#pragma unroll 1
    for (int o = t; o < ROWS * H_; o += 512) {
        const int r = o / H_;
        const int c = o - r * H_;
        float s = 0.0f;
#pragma unroll 4
        for (int k = 0; k < F_; k += 4) {
            const float4 hv = *reinterpret_cast<const float4*>(&hs[r][k]);
            s = fmaf(hv.x, W2[(k + 0) * H_ + c], s);
            s = fmaf(hv.y, W2[(k + 1) * H_ + c], s);
            s = fmaf(hv.z, W2[(k + 2) * H_ + c], s);
            s = fmaf(hv.w, W2[(k + 3) * H_ + c], s);
        }
        rwv[r][c] = s + b2[c];
    }
    __syncthreads();   // b2: rwv ready

    // ---- phase 3: combine ----
    f32x4 a0 = 0.f, a1 = 0.f, a2 = 0.f, a3 = 0.f;

    // (i) register-prefetched heads PFH..PFH+RPF-1
#pragma unroll
    for (int u = 0; u < RPF; ++u) {
        const int h = PFH + u;
        const float w0 = rwv[r0v + 0][h];
        const float w1 = rwv[r0v + 1][h];
        const float w2 = rwv[r0v + 2][h];
        const float w3 = rwv[r0v + 3][h];
#pragma unroll
        for (int j = 0; j < 4; ++j) {
            a0[j] = fmaf(w0, pv[u][0][j], a0[j]);
            a1[j] = fmaf(w1, pv[u][1][j], a1[j]);
            a2[j] = fmaf(w2, pv[u][2][j], a2[j]);
            a3[j] = fmaf(w3, pv[u][3][j], a3[j]);
        }
    }

    // (ii) global stream heads PFH+RPF..71 (NT, 16 KB spans)
#pragma unroll 2
    for (int h = PFH + RPF; h < H_; ++h) {
        const int ib = base + h * hstr;
        const f32x4 v0 = __builtin_nontemporal_load(sp + ib);
        const f32x4 v1 = __builtin_nontemporal_load(sp + ib + 256);
        const f32x4 v2 = __builtin_nontemporal_load(sp + ib + 512);
        const f32x4 v3 = __builtin_nontemporal_load(sp + ib + 768);
        const float w0 = rwv[r0v + 0][h];
        const float w1 = rwv[r0v + 1][h];
        const float w2 = rwv[r0v + 2][h];
        const float w3 = rwv[r0v + 3][h];
#pragma unroll
        for (int j = 0; j < 4; ++j) {
            a0[j] = fmaf(w0, v0[j], a0[j]);
            a1[j] = fmaf(w1, v1[j], a1[j]);
            a2[j] = fmaf(w2, v2[j], a2[j]);
            a3[j] = fmaf(w3, v3[j], a3[j]);
        }
    }

    // (iii) LDS-prefetched heads 0..PFH-1 (hides the global tail's latency)
#pragma unroll
    for (int h = 0; h < PFH; ++h) {
        const f32x4 v0 = *reinterpret_cast<const f32x4*>(&pf[h][r0v + 0][col * 4]);
        const f32x4 v1 = *reinterpret_cast<const f32x4*>(&pf[h][r0v + 1][col * 4]);
        const f32x4 v2 = *reinterpret_cast<const f32x4*>(&pf[h][r0v + 2][col * 4]);
        const f32x4 v3 = *reinterpret_cast<const f32x4*>(&pf[h][r0v + 3][col * 4]);
        const float w0 = rwv[r0v + 0][h];
        const float w1 = rwv[r0v + 1][h];
        const float w2 = rwv[r0v + 2][h];
        const float w3 = rwv[r0v + 3][h];
#pragma unroll
        for (int j = 0; j < 4; ++j) {
            a0[j] = fmaf(w0, v0[j], a0[j]);
            a1[j] = fmaf(w1, v1[j], a1[j]);
            a2[j] = fmaf(w2, v2[j], a2[j]);
            a3[j] = fmaf(w3, v3[j], a3[j]);
        }
    }

    const float bv = bias[0];
#pragma unroll
    for (int j = 0; j < 4; ++j) { a0[j] += bv; a1[j] += bv; a2[j] += bv; a3[j] += bv; }

    f32x4* __restrict__ op = reinterpret_cast<f32x4*>(out);
    const int obase = (row0 + r0v) * (M_ / 4) + col;
    __builtin_nontemporal_store(a0, op + obase);
    __builtin_nontemporal_store(a1, op + obase + 256);
    __builtin_nontemporal_store(a2, op + obase + 512);
    __builtin_nontemporal_store(a3, op + obase + 768);
}

extern "C" void kernel_launch(void* const* d_in, const int* in_sizes, int n_in,
                              void* d_out, int out_size, void* d_ws, size_t ws_size,
                              hipStream_t stream) {
    const float* x      = (const float*)d_in[0];
    const float* scores = (const float*)d_in[1];
    const float* W1     = (const float*)d_in[2];
    const float* b1     = (const float*)d_in[3];
    const float* W2     = (const float*)d_in[4];
    const float* b2     = (const float*)d_in[5];
    const float* bias   = (const float*)d_in[6];
    float* out = (float*)d_out;

    fused_kernel<<<(B_ * N_) / ROWS, 512, 0, stream>>>(
        x, scores, W1, b1, W2, b2, bias, out);
}

// Round 15
// 149.863 us; speedup vs baseline: 1.0866x; 1.0866x over previous
//
#include <hip/hip_runtime.h>
#include <math.h>

// DynamicElementAggregator: B=2, N=1024, M=1024, D=768, F=384, H=72
#define B_ 2
#define N_ 1024
#define M_ 1024
#define D_ 768
#define F_ 384
#define H_ 72

typedef float f32x4 __attribute__((ext_vector_type(4)));

// Raw router weights (2048 x 72, 576 KB). Fully rewritten every call.
__device__ float g_rw[B_ * N_ * H_];

// ---- K1: router MLP (unchanged from Round 5 — known-good) -----------------
__global__ __launch_bounds__(384) void mlp_kernel(
    const float* __restrict__ x, const float* __restrict__ W1,
    const float* __restrict__ b1, const float* __restrict__ W2,
    const float* __restrict__ b2)
{
    const int f = threadIdx.x;            // 0..383
    const int row0 = blockIdx.x * 8;

    __shared__ float xs[8][D_];           // 24 KB
    __shared__ float hs[8][F_ + 8];       // 12.25 KB, pitch 392

    {   // stage x rows (coalesced float4)
        const f32x4* xg = reinterpret_cast<const f32x4*>(x + row0 * D_);
        f32x4* xl = reinterpret_cast<f32x4*>(&xs[0][0]);
#pragma unroll
        for (int i = 0; i < 4; ++i)
            xl[threadIdx.x + i * 384] = xg[threadIdx.x + i * 384];
    }
    __syncthreads();

    float acc[8];
#pragma unroll
    for (int r = 0; r < 8; ++r) acc[r] = 0.0f;

#pragma unroll 4
    for (int d = 0; d < D_; d += 4) {
        const float w0 = W1[(d + 0) * F_ + f];
        const float w1v = W1[(d + 1) * F_ + f];
        const float w2v = W1[(d + 2) * F_ + f];
        const float w3v = W1[(d + 3) * F_ + f];
#pragma unroll
        for (int r = 0; r < 8; ++r) {
            const float4 xv = *reinterpret_cast<const float4*>(&xs[r][d]);
            acc[r] = fmaf(xv.x, w0, acc[r]);
            acc[r] = fmaf(xv.y, w1v, acc[r]);
            acc[r] = fmaf(xv.z, w2v, acc[r]);
            acc[r] = fmaf(xv.w, w3v, acc[r]);
        }
    }

    const float bb = b1[f];
#pragma unroll
    for (int r = 0; r < 8; ++r) {
        const float v = acc[r] + bb;
        hs[r][f] = 0.5f * v * (1.0f + erff(v * 0.70710678118654752f));
    }
    __syncthreads();

#pragma unroll 1
    for (int o = f; o < 8 * H_; o += 384) {
        const int r = o / H_;
        const int c = o - r * H_;
        float s = 0.0f;
#pragma unroll 4
        for (int k = 0; k < F_; k += 4) {
            const float4 hv = *reinterpret_cast<const float4*>(&hs[r][k]);
            s = fmaf(hv.x, W2[(k + 0) * H_ + c], s);
            s = fmaf(hv.y, W2[(k + 1) * H_ + c], s);
            s = fmaf(hv.z, W2[(k + 2) * H_ + c], s);
            s = fmaf(hv.w, W2[(k + 3) * H_ + c], s);
        }
        g_rw[row0 * H_ + o] = s + b2[c];
    }
}

// ---- K2: high-TLP slab combine ---------------------------------------------
// 512 blocks x 512 threads = 2 blocks/CU = 16 waves/CU (vs 8 in R5/R10).
// Block owns 4 consecutive rows (16 KB contiguous per head — R5-proven).
// Thread t: col = t&255 (float4), rows rp2 = (t>>8)*2 .. +1 (2 loads/head).
// Unroll 4 -> 8 NT loads in flight per wave; ~40 VGPR so 16 waves are real.
// GRID MUST BE 512: b = blk>>8, n0 = (blk&255)*4.
__global__ __launch_bounds__(512) void combine_kernel(
    const float* __restrict__ scores, const float* __restrict__ bias,
    float* __restrict__ out)
{
    const int blk = blockIdx.x;           // 0..511
    const int b = blk >> 8;               // 0..1
    const int n0 = (blk & 255) * 4;       // 0..1020
    const int t = threadIdx.x;

    __shared__ float w[4 * H_];           // weights for the 4 rows (1.125 KB)
    for (int i = t; i < 4 * H_; i += 512)
        w[i] = g_rw[((b << 10) + n0) * H_ + i];
    __syncthreads();

    const int col = t & 255;
    const int rp2 = (t >> 8) * 2;         // 0 or 2: this thread's first row

    const f32x4* __restrict__ sp = reinterpret_cast<const f32x4*>(scores);
    const int base = ((b * H_) * N_ + n0 + rp2) * (M_ / 4) + col;
    const int hstr = N_ * (M_ / 4);       // 262144 float4 per head panel

    f32x4 a0 = 0.f, a1 = 0.f;
#pragma unroll 4
    for (int h = 0; h < H_; ++h) {
        const int ib = base + h * hstr;
        const f32x4 v0 = __builtin_nontemporal_load(sp + ib);
        const f32x4 v1 = __builtin_nontemporal_load(sp + ib + 256);
        const float w0 = w[(rp2 + 0) * H_ + h];
        const float w1 = w[(rp2 + 1) * H_ + h];
#pragma unroll
        for (int j = 0; j < 4; ++j) {
            a0[j] = fmaf(w0, v0[j], a0[j]);
            a1[j] = fmaf(w1, v1[j], a1[j]);
        }
    }

    const float bv = bias[0];
#pragma unroll
    for (int j = 0; j < 4; ++j) { a0[j] += bv; a1[j] += bv; }

    f32x4* __restrict__ op = reinterpret_cast<f32x4*>(out);
    const int obase = ((b << 10) + n0 + rp2) * (M_ / 4) + col;
    __builtin_nontemporal_store(a0, op + obase);
    __builtin_nontemporal_store(a1, op + obase + 256);
}

extern "C" void kernel_launch(void* const* d_in, const int* in_sizes, int n_in,
                              void* d_out, int out_size, void* d_ws, size_t ws_size,
                              hipStream_t stream) {
    const float* x      = (const float*)d_in[0];
    const float* scores = (const float*)d_in[1];
    const float* W1     = (const float*)d_in[2];
    const float* b1     = (const float*)d_in[3];
    const float* W2     = (const float*)d_in[4];
    const float* b2     = (const float*)d_in[5];
    const float* bias   = (const float*)d_in[6];
    float* out = (float*)d_out;

    mlp_kernel<<<(B_ * N_) / 8, 384, 0, stream>>>(x, W1, b1, W2, b2);
    combine_kernel<<<(B_ * N_) / 4, 512, 0, stream>>>(scores, bias, out);
}

// Round 16
// 136.566 us; speedup vs baseline: 1.1924x; 1.0974x over previous
//
#include <hip/hip_runtime.h>
#include <math.h>

// DynamicElementAggregator: B=2, N=1024, M=1024, D=768, F=384, H=72
#define B_ 2
#define N_ 1024
#define M_ 1024
#define D_ 768
#define F_ 384
#define H_ 72
#define ROWS 8      // rows per block
#define PFH 3       // heads prefetched into LDS during the MLP phase

typedef float f32x4 __attribute__((ext_vector_type(4)));

// ---- Fully fused, wave-specialized (R10 base, rebalanced 192/320):
//   threads 0..191 (3 waves): layer-1, 2 hidden cols each (f, f+192)
//                             -> halves broadcast-LDS issue count vs R10
//   threads 192..511 (5 waves): stream heads 0..2 (96 KB) into LDS
// then all 512: layer-2 -> rwv, then slab combine (16 KB spans, NT).
// 256 blocks x 512 threads, 8 rows/block, 1 block/CU (134.75 KB LDS).
__global__ __launch_bounds__(512) void fused_kernel(
    const float* __restrict__ x, const float* __restrict__ scores,
    const float* __restrict__ W1, const float* __restrict__ b1,
    const float* __restrict__ W2, const float* __restrict__ b2,
    const float* __restrict__ bias, float* __restrict__ out)
{
    const int t = threadIdx.x;            // 0..511
    const int blk = blockIdx.x;           // 0..255
    const int b = blk >> 7;
    const int n0 = (blk & 127) * ROWS;
    const int row0 = (b << 10) + n0;      // global flattened row

    __shared__ float xs[ROWS][D_];            // 24 KB
    __shared__ float hs[ROWS][F_ + 8];        // 12.25 KB (pitch 392)
    __shared__ float rwv[ROWS][80];           // 2.5 KB
    __shared__ float pf[PFH][ROWS][M_];       // 96 KB

    const f32x4* __restrict__ sp = reinterpret_cast<const f32x4*>(scores);
    const int hstr = N_ * (M_ / 4);           // float4 per head panel
    const int sbase = ((b * H_) * N_ + n0) * (M_ / 4);  // (b, h=0, n0, 0)

    // ---- phase 0: stage x rows into LDS (1536 float4 / 512 threads) ----
    {
        const f32x4* xg = reinterpret_cast<const f32x4*>(x + row0 * D_);
        f32x4* xl = reinterpret_cast<f32x4*>(&xs[0][0]);
#pragma unroll
        for (int i = 0; i < 3; ++i)
            xl[t + i * 512] = xg[t + i * 512];
    }
    __syncthreads();   // b0: xs ready

    // ---- phase 1: layer-1 (t<192, 2 cols) || LDS prefetch (t>=192) ----
    if (t < 192) {
        const int f = t;                  // cols f and f+192
        float acc0[ROWS], acc1[ROWS];
#pragma unroll
        for (int r = 0; r < ROWS; ++r) { acc0[r] = 0.0f; acc1[r] = 0.0f; }

#pragma unroll 4
        for (int d = 0; d < D_; d += 4) {
            float wa[4], wb[4];
#pragma unroll
            for (int i = 0; i < 4; ++i) {
                wa[i] = W1[(d + i) * F_ + f];
                wb[i] = W1[(d + i) * F_ + f + 192];
            }
#pragma unroll
            for (int r = 0; r < ROWS; ++r) {
                const float4 xv = *reinterpret_cast<const float4*>(&xs[r][d]);
                acc0[r] = fmaf(xv.x, wa[0], acc0[r]);
                acc0[r] = fmaf(xv.y, wa[1], acc0[r]);
                acc0[r] = fmaf(xv.z, wa[2], acc0[r]);
                acc0[r] = fmaf(xv.w, wa[3], acc0[r]);
                acc1[r] = fmaf(xv.x, wb[0], acc1[r]);
                acc1[r] = fmaf(xv.y, wb[1], acc1[r]);
                acc1[r] = fmaf(xv.z, wb[2], acc1[r]);
                acc1[r] = fmaf(xv.w, wb[3], acc1[r]);
            }
        }
        const float ba = b1[f];
        const float bb = b1[f + 192];
#pragma unroll
        for (int r = 0; r < ROWS; ++r) {
            const float v0 = acc0[r] + ba;
            const float v1 = acc1[r] + bb;
            hs[r][f]       = 0.5f * v0 * (1.0f + erff(v0 * 0.70710678118654752f));
            hs[r][f + 192] = 0.5f * v1 * (1.0f + erff(v1 * 0.70710678118654752f));
        }
    } else {
        // 320 threads stream PFH*ROWS*256 = 6144 float4 (96 KB) into pf.
        const int j = t - 192;                // 0..319
        f32x4* pfl = reinterpret_cast<f32x4*>(&pf[0][0][0]);
#pragma unroll 4
        for (int i = j; i < PFH * ROWS * 256; i += 320) {
            const int h = i >> 11;            // / (ROWS*256)
            const int rem = i & 2047;         // r*256 + c
            pfl[i] = __builtin_nontemporal_load(sp + sbase + h * hstr + rem);
        }
    }
    __syncthreads();   // b1: hs + pf ready

    // ---- phase 2: layer-2 (all 512 threads, 576 outputs) ----
#pragma unroll 1
    for (int o = t; o < ROWS * H_; o += 512) {
        const int r = o / H_;
        const int c = o - r * H_;
        float s = 0.0f;
#pragma unroll 4
        for (int k = 0; k < F_; k += 4) {
            const float4 hv = *reinterpret_cast<const float4*>(&hs[r][k]);
            s = fmaf(hv.x, W2[(k + 0) * H_ + c], s);
            s = fmaf(hv.y, W2[(k + 1) * H_ + c], s);
            s = fmaf(hv.z, W2[(k + 2) * H_ + c], s);
            s = fmaf(hv.w, W2[(k + 3) * H_ + c], s);
        }
        rwv[r][c] = s + b2[c];
    }
    __syncthreads();   // b2: rwv ready

    // ---- phase 3: combine. t -> (rows r0v..r0v+3, float4-col) ----
    const int col = t & 255;
    const int r0v = (t >> 8) * 4;             // 0 or 4

    const int base = sbase + r0v * (M_ / 4) + col;

    f32x4 a0 = 0.f, a1 = 0.f, a2 = 0.f, a3 = 0.f;
    // global heads PFH..71 (NT, 16 KB contiguous per head per block)
#pragma unroll 2
    for (int h = PFH; h < H_; ++h) {
        const int ib = base + h * hstr;
        const f32x4 v0 = __builtin_nontemporal_load(sp + ib);
        const f32x4 v1 = __builtin_nontemporal_load(sp + ib + 256);
        const f32x4 v2 = __builtin_nontemporal_load(sp + ib + 512);
        const f32x4 v3 = __builtin_nontemporal_load(sp + ib + 768);
        const float w0 = rwv[r0v + 0][h];
        const float w1 = rwv[r0v + 1][h];
        const float w2 = rwv[r0v + 2][h];
        const float w3 = rwv[r0v + 3][h];
#pragma unroll
        for (int j = 0; j < 4; ++j) {
            a0[j] = fmaf(w0, v0[j], a0[j]);
            a1[j] = fmaf(w1, v1[j], a1[j]);
            a2[j] = fmaf(w2, v2[j], a2[j]);
            a3[j] = fmaf(w3, v3[j], a3[j]);
        }
    }
    // LDS heads 0..PFH-1 (prefetched during the MLP phase)
#pragma unroll
    for (int h = 0; h < PFH; ++h) {
        const f32x4 v0 = *reinterpret_cast<const f32x4*>(&pf[h][r0v + 0][col * 4]);
        const f32x4 v1 = *reinterpret_cast<const f32x4*>(&pf[h][r0v + 1][col * 4]);
        const f32x4 v2 = *reinterpret_cast<const f32x4*>(&pf[h][r0v + 2][col * 4]);
        const f32x4 v3 = *reinterpret_cast<const f32x4*>(&pf[h][r0v + 3][col * 4]);
        const float w0 = rwv[r0v + 0][h];
        const float w1 = rwv[r0v + 1][h];
        const float w2 = rwv[r0v + 2][h];
        const float w3 = rwv[r0v + 3][h];
#pragma unroll
        for (int j = 0; j < 4; ++j) {
            a0[j] = fmaf(w0, v0[j], a0[j]);
            a1[j] = fmaf(w1, v1[j], a1[j]);
            a2[j] = fmaf(w2, v2[j], a2[j]);
            a3[j] = fmaf(w3, v3[j], a3[j]);
        }
    }

    const float bv = bias[0];
#pragma unroll
    for (int j = 0; j < 4; ++j) { a0[j] += bv; a1[j] += bv; a2[j] += bv; a3[j] += bv; }

    f32x4* __restrict__ op = reinterpret_cast<f32x4*>(out);
    const int obase = (row0 + r0v) * (M_ / 4) + col;
    __builtin_nontemporal_store(a0, op + obase);
    __builtin_nontemporal_store(a1, op + obase + 256);
    __builtin_nontemporal_store(a2, op + obase + 512);
    __builtin_nontemporal_store(a3, op + obase + 768);
}

extern "C" void kernel_launch(void* const* d_in, const int* in_sizes, int n_in,
                              void* d_out, int out_size, void* d_ws, size_t ws_size,
                              hipStream_t stream) {
    const float* x      = (const float*)d_in[0];
    const float* scores = (const float*)d_in[1];
    const float* W1     = (const float*)d_in[2];
    const float* b1     = (const float*)d_in[3];
    const float* W2     = (const float*)d_in[4];
    const float* b2     = (const float*)d_in[5];
    const float* bias   = (const float*)d_in[6];
    float* out = (float*)d_out;

    fused_kernel<<<(B_ * N_) / ROWS, 512, 0, stream>>>(
        x, scores, W1, b1, W2, b2, bias, out);
}

// Round 17
// 136.469 us; speedup vs baseline: 1.1932x; 1.0007x over previous
//
#include <hip/hip_runtime.h>
#include <math.h>

// DynamicElementAggregator: B=2, N=1024, M=1024, D=768, F=384, H=72
#define B_ 2
#define N_ 1024
#define M_ 1024
#define D_ 768
#define F_ 384
#define H_ 72
#define ROWS 8      // rows per block
#define PFH 6       // heads prefetched into LDS (as bf16) during MLP phase

typedef float f32x4 __attribute__((ext_vector_type(4)));
typedef unsigned short u16x4 __attribute__((ext_vector_type(4)));

// ---- Fully fused, wave-specialized (R16 base + bf16 LDS prefetch, PFH=6):
//   threads 0..191 (3 waves): layer-1, 2 hidden cols each
//   threads 192..511 (5 waves): stream heads 0..5 into LDS as bf16 (96 KB)
// then all 512: layer-2 -> rwv, then slab combine (16 KB spans, NT).
// 256 blocks x 512 threads, 8 rows/block, 1 block/CU (134.75 KB LDS).
__global__ __launch_bounds__(512) void fused_kernel(
    const float* __restrict__ x, const float* __restrict__ scores,
    const float* __restrict__ W1, const float* __restrict__ b1,
    const float* __restrict__ W2, const float* __restrict__ b2,
    const float* __restrict__ bias, float* __restrict__ out)
{
    const int t = threadIdx.x;            // 0..511
    const int blk = blockIdx.x;           // 0..255
    const int b = blk >> 7;
    const int n0 = (blk & 127) * ROWS;
    const int row0 = (b << 10) + n0;      // global flattened row

    __shared__ float xs[ROWS][D_];            // 24 KB
    __shared__ float hs[ROWS][F_ + 8];        // 12.25 KB (pitch 392)
    __shared__ float rwv[ROWS][80];           // 2.5 KB
    __shared__ unsigned short pf16[PFH][ROWS][M_];  // 96 KB (bf16 scores)

    const f32x4* __restrict__ sp = reinterpret_cast<const f32x4*>(scores);
    const int hstr = N_ * (M_ / 4);           // float4 per head panel
    const int sbase = ((b * H_) * N_ + n0) * (M_ / 4);  // (b, h=0, n0, 0)

    // ---- phase 0: stage x rows into LDS (1536 float4 / 512 threads) ----
    {
        const f32x4* xg = reinterpret_cast<const f32x4*>(x + row0 * D_);
        f32x4* xl = reinterpret_cast<f32x4*>(&xs[0][0]);
#pragma unroll
        for (int i = 0; i < 3; ++i)
            xl[t + i * 512] = xg[t + i * 512];
    }
    __syncthreads();   // b0: xs ready

    // ---- phase 1: layer-1 (t<192, 2 cols) || bf16 prefetch (t>=192) ----
    if (t < 192) {
        const int f = t;                  // cols f and f+192
        float acc0[ROWS], acc1[ROWS];
#pragma unroll
        for (int r = 0; r < ROWS; ++r) { acc0[r] = 0.0f; acc1[r] = 0.0f; }

#pragma unroll 4
        for (int d = 0; d < D_; d += 4) {
            float wa[4], wb[4];
#pragma unroll
            for (int i = 0; i < 4; ++i) {
                wa[i] = W1[(d + i) * F_ + f];
                wb[i] = W1[(d + i) * F_ + f + 192];
            }
#pragma unroll
            for (int r = 0; r < ROWS; ++r) {
                const float4 xv = *reinterpret_cast<const float4*>(&xs[r][d]);
                acc0[r] = fmaf(xv.x, wa[0], acc0[r]);
                acc0[r] = fmaf(xv.y, wa[1], acc0[r]);
                acc0[r] = fmaf(xv.z, wa[2], acc0[r]);
                acc0[r] = fmaf(xv.w, wa[3], acc0[r]);
                acc1[r] = fmaf(xv.x, wb[0], acc1[r]);
                acc1[r] = fmaf(xv.y, wb[1], acc1[r]);
                acc1[r] = fmaf(xv.z, wb[2], acc1[r]);
                acc1[r] = fmaf(xv.w, wb[3], acc1[r]);
            }
        }
        const float ba = b1[f];
        const float bb = b1[f + 192];
#pragma unroll
        for (int r = 0; r < ROWS; ++r) {
            const float v0 = acc0[r] + ba;
            const float v1 = acc1[r] + bb;
            hs[r][f]       = 0.5f * v0 * (1.0f + erff(v0 * 0.70710678118654752f));
            hs[r][f + 192] = 0.5f * v1 * (1.0f + erff(v1 * 0.70710678118654752f));
        }
    } else {
        // 320 threads stream PFH*ROWS*256 = 12288 float4 (192 KB f32),
        // converting to bf16 (round-half-up) -> 96 KB LDS.
        const int j = t - 192;                // 0..319
        u16x4* pfl = reinterpret_cast<u16x4*>(&pf16[0][0][0]);  // 12288 u16x4
#pragma unroll 4
        for (int i = j; i < PFH * ROWS * 256; i += 320) {
            const int h = i >> 11;            // / (ROWS*256)
            const int rem = i & 2047;         // r*256 + c
            const f32x4 v =
                __builtin_nontemporal_load(sp + sbase + h * hstr + rem);
            u16x4 u;
#pragma unroll
            for (int k = 0; k < 4; ++k)
                u[k] = (unsigned short)((__float_as_uint(v[k]) + 0x8000u) >> 16);
            pfl[i] = u;
        }
    }
    __syncthreads();   // b1: hs + pf16 ready

    // ---- phase 2: layer-2 (all 512 threads, 576 outputs) ----
#pragma unroll 1
    for (int o = t; o < ROWS * H_; o += 512) {
        const int r = o / H_;
        const int c = o - r * H_;
        float s = 0.0f;
#pragma unroll 4
        for (int k = 0; k < F_; k += 4) {
            const float4 hv = *reinterpret_cast<const float4*>(&hs[r][k]);
            s = fmaf(hv.x, W2[(k + 0) * H_ + c], s);
            s = fmaf(hv.y, W2[(k + 1) * H_ + c], s);
            s = fmaf(hv.z, W2[(k + 2) * H_ + c], s);
            s = fmaf(hv.w, W2[(k + 3) * H_ + c], s);
        }
        rwv[r][c] = s + b2[c];
    }
    __syncthreads();   // b2: rwv ready

    // ---- phase 3: combine. t -> (rows r0v..r0v+3, float4-col) ----
    const int col = t & 255;
    const int r0v = (t >> 8) * 4;             // 0 or 4

    const int base = sbase + r0v * (M_ / 4) + col;

    f32x4 a0 = 0.f, a1 = 0.f, a2 = 0.f, a3 = 0.f;
    // global heads PFH..71 (NT, 16 KB contiguous per head per block)
#pragma unroll 2
    for (int h = PFH; h < H_; ++h) {
        const int ib = base + h * hstr;
        const f32x4 v0 = __builtin_nontemporal_load(sp + ib);
        const f32x4 v1 = __builtin_nontemporal_load(sp + ib + 256);
        const f32x4 v2 = __builtin_nontemporal_load(sp + ib + 512);
        const f32x4 v3 = __builtin_nontemporal_load(sp + ib + 768);
        const float w0 = rwv[r0v + 0][h];
        const float w1 = rwv[r0v + 1][h];
        const float w2 = rwv[r0v + 2][h];
        const float w3 = rwv[r0v + 3][h];
#pragma unroll
        for (int j = 0; j < 4; ++j) {
            a0[j] = fmaf(w0, v0[j], a0[j]);
            a1[j] = fmaf(w1, v1[j], a1[j]);
            a2[j] = fmaf(w2, v2[j], a2[j]);
            a3[j] = fmaf(w3, v3[j], a3[j]);
        }
    }
    // LDS heads 0..PFH-1 (bf16 -> f32 via <<16)
#pragma unroll
    for (int h = 0; h < PFH; ++h) {
        const u16x4 u0 = *reinterpret_cast<const u16x4*>(&pf16[h][r0v + 0][col * 4]);
        const u16x4 u1 = *reinterpret_cast<const u16x4*>(&pf16[h][r0v + 1][col * 4]);
        const u16x4 u2 = *reinterpret_cast<const u16x4*>(&pf16[h][r0v + 2][col * 4]);
        const u16x4 u3 = *reinterpret_cast<const u16x4*>(&pf16[h][r0v + 3][col * 4]);
        const float w0 = rwv[r0v + 0][h];
        const float w1 = rwv[r0v + 1][h];
        const float w2 = rwv[r0v + 2][h];
        const float w3 = rwv[r0v + 3][h];
#pragma unroll
        for (int j = 0; j < 4; ++j) {
            a0[j] = fmaf(w0, __uint_as_float((unsigned)u0[j] << 16), a0[j]);
            a1[j] = fmaf(w1, __uint_as_float((unsigned)u1[j] << 16), a1[j]);
            a2[j] = fmaf(w2, __uint_as_float((unsigned)u2[j] << 16), a2[j]);
            a3[j] = fmaf(w3, __uint_as_float((unsigned)u3[j] << 16), a3[j]);
        }
    }

    const float bv = bias[0];
#pragma unroll
    for (int j = 0; j < 4; ++j) { a0[j] += bv; a1[j] += bv; a2[j] += bv; a3[j] += bv; }

    f32x4* __restrict__ op = reinterpret_cast<f32x4*>(out);
    const int obase = (row0 + r0v) * (M_ / 4) + col;
    __builtin_nontemporal_store(a0, op + obase);
    __builtin_nontemporal_store(a1, op + obase + 256);
    __builtin_nontemporal_store(a2, op + obase + 512);
    __builtin_nontemporal_store(a3, op + obase + 768);
}

extern "C" void kernel_launch(void* const* d_in, const int* in_sizes, int n_in,
                              void* d_out, int out_size, void* d_ws, size_t ws_size,
                              hipStream_t stream) {
    const float* x      = (const float*)d_in[0];
    const float* scores = (const float*)d_in[1];
    const float* W1     = (const float*)d_in[2];
    const float* b1     = (const float*)d_in[3];
    const float* W2     = (const float*)d_in[4];
    const float* b2     = (const float*)d_in[5];
    const float* bias   = (const float*)d_in[6];
    float* out = (float*)d_out;

    fused_kernel<<<(B_ * N_) / ROWS, 512, 0, stream>>>(
        x, scores, W1, b1, W2, b2, bias, out);
}